// Round 1
// baseline (51.427 us; speedup 1.0000x reference)
//
#include <hip/hip_runtime.h>
#include <math.h>

// One item (pentachoron) per 8-lane group: 8 items per wave, 32 per block(256).
// Phase 1: fp64 partial sums of 10 pairwise dist^2 + 5 centroid dist^2,
//          16 dims per lane, butterfly-reduced over the 8-lane group.
// Phase 2: fp64 Cayley-Menger det (static-index LU), edge/spread stats,
//          sigmoids, 8-step Cantor iteration. All lanes of a group compute
//          redundantly; lane s==0 stores.

__global__ __launch_bounds__(256) void fingerprint_kernel(
    const float* __restrict__ pent, float* __restrict__ out, int nItems)
{
    const int tid  = threadIdx.x;
    const int wave = tid >> 6;
    const int lane = tid & 63;
    const int grp  = lane >> 3;   // which of the wave's 8 items
    const int s    = lane & 7;    // slice within the item

    long item  = (long)blockIdx.x * 32 + (long)wave * 8 + grp;
    long itemC = item < nItems ? item : (long)nItems - 1;

    const float4* __restrict__ p =
        reinterpret_cast<const float4*>(pent + itemC * 640L);

    // Load 5 rows x 512B; per (v,j) instruction: lanes s=0..7 cover a
    // contiguous 128B chunk per item -> coalesced (16 full 64B lines/instr).
    float4 f[5][4];
#pragma unroll
    for (int v = 0; v < 5; ++v)
#pragma unroll
        for (int j = 0; j < 4; ++j)
            f[v][j] = p[v * 32 + j * 8 + s];

    const float* fp = reinterpret_cast<const float*>(f);

    double sp[10];   // pair dist^2 partials, triu order (0,1)..(3,4)
    double sc[5];    // centroid dist^2 partials
#pragma unroll
    for (int q = 0; q < 10; ++q) sp[q] = 0.0;
#pragma unroll
    for (int v = 0; v < 5; ++v)  sc[v] = 0.0;

#pragma unroll
    for (int t = 0; t < 16; ++t) {           // this lane's 16 dims
        double a[5];
#pragma unroll
        for (int v = 0; v < 5; ++v)
            a[v] = (double)fp[v * 16 + t];
        int q = 0;
#pragma unroll
        for (int i = 0; i < 5; ++i)
#pragma unroll
            for (int j = i + 1; j < 5; ++j) {
                double d = a[i] - a[j];
                sp[q] = fma(d, d, sp[q]);
                ++q;
            }
        double c = (a[0] + a[1] + a[2] + a[3] + a[4]) * 0.2;
#pragma unroll
        for (int v = 0; v < 5; ++v) {
            double d = a[v] - c;
            sc[v] = fma(d, d, sc[v]);
        }
    }

    // Butterfly reduce within the 8-lane group (masks 1,2,4).
#pragma unroll
    for (int m = 1; m <= 4; m <<= 1) {
#pragma unroll
        for (int q = 0; q < 10; ++q) sp[q] += __shfl_xor(sp[q], m, 64);
#pragma unroll
        for (int v = 0; v < 5; ++v)  sc[v] += __shfl_xor(sc[v], m, 64);
    }

    // ---- Phase 2 (redundant across the 8 lanes of the group) ----

    // Cayley-Menger matrix with rows 0 and 1 pre-swapped (M[0][0]=0 would
    // kill unpivoted LU). sign = -1 from the swap.
    double A[6][6];
    // original row1 -> A[0]
    A[0][0] = 1.0; A[0][1] = 0.0;
    // original row0 -> A[1]
    A[1][0] = 0.0; A[1][1] = 1.0;
#pragma unroll
    for (int j = 2; j < 6; ++j) { A[1][j] = 1.0; }
#pragma unroll
    for (int i = 2; i < 6; ++i) { A[i][0] = 1.0; A[i][i] = 0.0; }
    {
        int q = 0;
#pragma unroll
        for (int i = 0; i < 5; ++i)
#pragma unroll
            for (int j = i + 1; j < 5; ++j) {
                // dist_sq(i,j) sits at M[1+i][1+j]; after the row swap,
                // row (1+i) moved to index (1+i==1 ? 0 : 1+i).
                int ri = (i == 0) ? 0 : (1 + i);
                int rj = (j == 0) ? 0 : (1 + j);
                A[ri][1 + j] = sp[q];
                A[rj][1 + i] = sp[q];
                ++q;
            }
    }

    // Unpivoted LU, static indices only.
    double det = -1.0;   // one row swap
#pragma unroll
    for (int k = 0; k < 6; ++k) {
        double pv = A[k][k];
        det *= pv;
        double inv = (pv != 0.0) ? 1.0 / pv : 0.0;
#pragma unroll
        for (int r = k + 1; r < 6; ++r) {
            double fac = A[r][k] * inv;
#pragma unroll
            for (int c = k + 1; c < 6; ++c)
                A[r][c] = fma(-fac, A[k][c], A[r][c]);
        }
    }

    double v2 = -det / 9216.0;
    double volume = (v2 > 0.0) ? sqrt(v2) : 0.0;

    // Edge statistics (ddof=1 over 10 edges).
    double e[10], se = 0.0;
#pragma unroll
    for (int q = 0; q < 10; ++q) { e[q] = sqrt(sp[q]); se += e[q]; }
    double meanE = se * 0.1;
    double ve = 0.0;
#pragma unroll
    for (int q = 0; q < 10; ++q) { double d = e[q] - meanE; ve = fma(d, d, ve); }
    double stdE = sqrt(ve / 9.0);

    // Vertex spread (ddof=1 over 5 centroid distances).
    double cd[5], scd = 0.0;
#pragma unroll
    for (int v = 0; v < 5; ++v) { cd[v] = sqrt(sc[v]); scd += cd[v]; }
    double meanC = scd * 0.2;
    double vc = 0.0;
#pragma unroll
    for (int v = 0; v < 5; ++v) { double d = cd[v] - meanC; vc = fma(d, d, vc); }
    double spread = sqrt(vc * 0.25);

    double vn = 1.0 / (1.0 + exp(-10.0 * volume));
    double er = 1.0 / (1.0 + exp(-(stdE / (meanE + 1e-6))));
    double sn = 1.0 / (1.0 + exp(-spread));

    double seed = 0.4 * vn + 0.3 * er + 0.3 * sn;
    seed = fmin(fmax(seed, 1e-6), 1.0 - 1e-6);
    double drift = (vn + er + sn) * 0.01;

    double x = seed, cv = 0.0, factor = 0.5;
#pragma unroll
    for (int k = 0; k < 8; ++k) {
        double xs = x * 3.0;
        double dg = floor(xs);
        double fr = xs - dg;
        cv += (dg == 2.0) ? factor : 0.0;
        factor *= 0.5;
        x = fmin(fmax(fr + drift, 1e-6), 1.0 - 1e-6);
    }
    cv = fmin(fmax(cv, 0.0), 1.0);

    if (s == 0 && item < nItems)
        out[item] = (float)cv;
}

extern "C" void kernel_launch(void* const* d_in, const int* in_sizes, int n_in,
                              void* d_out, int out_size, void* d_ws, size_t ws_size,
                              hipStream_t stream) {
    const float* pent = (const float*)d_in[0];
    float* out = (float*)d_out;
    int nItems = in_sizes[0] / 640;            // 5*128 floats per item
    int blocks = (nItems + 31) / 32;           // 32 items per 256-thread block
    hipLaunchKernelGGL(fingerprint_kernel, dim3(blocks), dim3(256), 0, stream,
                       pent, out, nItems);
}

// Round 2
// 49.364 us; speedup vs baseline: 1.0418x; 1.0418x over previous
//
#include <hip/hip_runtime.h>
#include <math.h>

// One item (pentachoron) per 8-lane group: 8 items/wave, 32 per 256-block.
// Phase 1: fp64 Gram accumulation (15 dots G[i][j], i<=j), 16 dims/lane,
//          butterfly-reduced over the 8-lane group (masks 1,2,4).
// Phase 2 (redundant in-group, fp64):
//          dist^2 = Gii+Gjj-2Gij;  cdist^2_p = Gpp - 0.4*S_p + 0.04*T;
//          Cayley-Menger det reduced analytically: det M6 = -16 det W,
//          W[pq] = Gpq - G0p - G0q + G00 (4x4 PSD -> unpivoted LU),
//          volume^2 = det W / 576.  Then stats, sigmoids, Cantor iteration.

__global__ __launch_bounds__(256) void fingerprint_kernel(
    const float* __restrict__ pent, float* __restrict__ out, int nItems)
{
    const int tid  = threadIdx.x;
    const int wave = tid >> 6;
    const int lane = tid & 63;
    const int grp  = lane >> 3;   // which of the wave's 8 items
    const int s    = lane & 7;    // slice within the item

    long item  = (long)blockIdx.x * 32 + (long)wave * 8 + grp;
    long itemC = item < nItems ? item : (long)nItems - 1;

    const float4* __restrict__ p =
        reinterpret_cast<const float4*>(pent + itemC * 640L);

    // 20 x global_load_dwordx4; per (v,j) instruction lanes s=0..7 cover a
    // contiguous 128B chunk per item -> fully coalesced.
    float4 f[5][4];
#pragma unroll
    for (int v = 0; v < 5; ++v)
#pragma unroll
        for (int j = 0; j < 4; ++j)
            f[v][j] = p[v * 32 + j * 8 + s];

    const float* fp = reinterpret_cast<const float*>(f);

    // 15 Gram partials: order (0,0)..(0,4),(1,1)..(1,4),(2,2)..,(3,3),(3,4),(4,4)
    double g[15];
#pragma unroll
    for (int q = 0; q < 15; ++q) g[q] = 0.0;

#pragma unroll
    for (int t = 0; t < 16; ++t) {           // this lane's 16 dims
        double a[5];
#pragma unroll
        for (int v = 0; v < 5; ++v)
            a[v] = (double)fp[v * 16 + t];
        int q = 0;
#pragma unroll
        for (int i = 0; i < 5; ++i)
#pragma unroll
            for (int j = i; j < 5; ++j) {
                g[q] = fma(a[i], a[j], g[q]);
                ++q;
            }
    }

    // Butterfly reduce within the 8-lane group.
#pragma unroll
    for (int m = 1; m <= 4; m <<= 1)
#pragma unroll
        for (int q = 0; q < 15; ++q) g[q] += __shfl_xor(g[q], m, 64);

    // ---- Phase 2 (redundant across the 8 lanes of the group) ----

    // Expand to full symmetric G[5][5] (static indices).
    double G[5][5];
    {
        int q = 0;
#pragma unroll
        for (int i = 0; i < 5; ++i)
#pragma unroll
            for (int j = i; j < 5; ++j) {
                G[i][j] = g[q];
                G[j][i] = g[q];
                ++q;
            }
    }

    // Row sums and total.
    double S[5], T = 0.0;
#pragma unroll
    for (int i = 0; i < 5; ++i) {
        S[i] = G[i][0] + G[i][1] + G[i][2] + G[i][3] + G[i][4];
        T += S[i];
    }

    // 10 pairwise squared distances, triu order.
    double d2[10];
    {
        int q = 0;
#pragma unroll
        for (int i = 0; i < 5; ++i)
#pragma unroll
            for (int j = i + 1; j < 5; ++j) {
                d2[q] = fma(-2.0, G[i][j], G[i][i] + G[j][j]);
                ++q;
            }
    }

    // W[pq] = (x_p - x_0)·(x_q - x_0), p,q in 1..4 (4x4, PSD).
    double W[4][4];
#pragma unroll
    for (int pi = 0; pi < 4; ++pi)
#pragma unroll
        for (int qi = 0; qi < 4; ++qi)
            W[pi][qi] = G[pi + 1][qi + 1] - G[0][qi + 1] - G[pi + 1][0] + G[0][0];

    // Unpivoted LU on W (PSD -> positive pivots), det = prod of pivots.
    double det = 1.0;
#pragma unroll
    for (int k = 0; k < 4; ++k) {
        double pv = W[k][k];
        det *= pv;
        double inv = (pv != 0.0) ? 1.0 / pv : 0.0;
#pragma unroll
        for (int r = k + 1; r < 4; ++r) {
            double fac = W[r][k] * inv;
#pragma unroll
            for (int c = k + 1; c < 4; ++c)
                W[r][c] = fma(-fac, W[k][c], W[r][c]);
        }
    }

    double v2 = det / 576.0;                 // = -det(M6)/9216
    double volume = (v2 > 0.0) ? sqrt(v2) : 0.0;

    // Edge statistics (ddof=1 over 10 edges).
    double e[10], se = 0.0;
#pragma unroll
    for (int q = 0; q < 10; ++q) { e[q] = sqrt(d2[q]); se += e[q]; }
    double meanE = se * 0.1;
    double ve = 0.0;
#pragma unroll
    for (int q = 0; q < 10; ++q) { double d = e[q] - meanE; ve = fma(d, d, ve); }
    double stdE = sqrt(ve / 9.0);

    // Vertex spread (ddof=1 over 5 centroid distances).
    double cd[5], scd = 0.0;
#pragma unroll
    for (int v = 0; v < 5; ++v) {
        double c2 = fma(-0.4, S[v], G[v][v]) + 0.04 * T;
        cd[v] = (c2 > 0.0) ? sqrt(c2) : 0.0;
        scd += cd[v];
    }
    double meanC = scd * 0.2;
    double vc = 0.0;
#pragma unroll
    for (int v = 0; v < 5; ++v) { double d = cd[v] - meanC; vc = fma(d, d, vc); }
    double spread = sqrt(vc * 0.25);

    double vn = 1.0 / (1.0 + exp(-10.0 * volume));
    double er = 1.0 / (1.0 + exp(-(stdE / (meanE + 1e-6))));
    double sn = 1.0 / (1.0 + exp(-spread));

    double seed = 0.4 * vn + 0.3 * er + 0.3 * sn;
    seed = fmin(fmax(seed, 1e-6), 1.0 - 1e-6);
    double drift = (vn + er + sn) * 0.01;

    double x = seed, cv = 0.0, factor = 0.5;
#pragma unroll
    for (int k = 0; k < 8; ++k) {
        double xs = x * 3.0;
        double dg = floor(xs);
        double fr = xs - dg;
        cv += (dg == 2.0) ? factor : 0.0;
        factor *= 0.5;
        x = fmin(fmax(fr + drift, 1e-6), 1.0 - 1e-6);
    }
    cv = fmin(fmax(cv, 0.0), 1.0);

    if (s == 0 && item < nItems)
        out[item] = (float)cv;
}

extern "C" void kernel_launch(void* const* d_in, const int* in_sizes, int n_in,
                              void* d_out, int out_size, void* d_ws, size_t ws_size,
                              hipStream_t stream) {
    const float* pent = (const float*)d_in[0];
    float* out = (float*)d_out;
    int nItems = in_sizes[0] / 640;            // 5*128 floats per item
    int blocks = (nItems + 31) / 32;           // 32 items per 256-thread block
    hipLaunchKernelGGL(fingerprint_kernel, dim3(blocks), dim3(256), 0, stream,
                       pent, out, nItems);
}

// Round 3
// 45.108 us; speedup vs baseline: 1.1401x; 1.0943x over previous
//
#include <hip/hip_runtime.h>
#include <math.h>

// Phase 1: one item per 8-lane group (8 items/wave, 32/block). fp64 Gram
//          accumulation (15 dots), 16 dims/lane, butterfly reduce (1,2,4).
//          Group lane 0 writes g[15] to LDS.
// Phase 2: ONE wave per block, one item per lane (32 lanes active): reads
//          g[15] from LDS, computes edge stats, spread, det(W) via 4x4 LU
//          (det M6 = -16 det W, vol^2 = det W/576), sigmoids, Cantor chain.
// All math fp64 (Cantor map amplifies seed error by 3^8; need ~1e-10).

__device__ __forceinline__ constexpr int gidx(int i, int j) {
    // upper-triangular (i<=j) index into g[15]
    return i * 5 - i * (i - 1) / 2 + (j - i);
}

__global__ __launch_bounds__(256, 4) void fingerprint_kernel(
    const float* __restrict__ pent, float* __restrict__ out, int nItems)
{
    __shared__ double lds_g[32][15];   // 3840 B; stride 120 B -> 2-way banks (free)

    const int tid  = threadIdx.x;
    const int wave = tid >> 6;
    const int lane = tid & 63;
    const int grp  = lane >> 3;   // which of the wave's 8 items
    const int s    = lane & 7;    // slice within the item

    long item  = (long)blockIdx.x * 32 + (long)wave * 8 + grp;
    long itemC = item < nItems ? item : (long)nItems - 1;

    const float4* __restrict__ p =
        reinterpret_cast<const float4*>(pent + itemC * 640L);

    // 20 x global_load_dwordx4; per (v,j) instruction lanes s=0..7 cover a
    // contiguous 128B chunk per item -> fully coalesced.
    float4 f[5][4];
#pragma unroll
    for (int v = 0; v < 5; ++v)
#pragma unroll
        for (int j = 0; j < 4; ++j)
            f[v][j] = p[v * 32 + j * 8 + s];

    const float* fp = reinterpret_cast<const float*>(f);

    double g[15];
#pragma unroll
    for (int q = 0; q < 15; ++q) g[q] = 0.0;

#pragma unroll
    for (int t = 0; t < 16; ++t) {           // this lane's 16 dims
        double a[5];
#pragma unroll
        for (int v = 0; v < 5; ++v)
            a[v] = (double)fp[v * 16 + t];
        int q = 0;
#pragma unroll
        for (int i = 0; i < 5; ++i)
#pragma unroll
            for (int j = i; j < 5; ++j) {
                g[q] = fma(a[i], a[j], g[q]);
                ++q;
            }
    }

    // Butterfly reduce within the 8-lane group.
#pragma unroll
    for (int m = 1; m <= 4; m <<= 1)
#pragma unroll
        for (int q = 0; q < 15; ++q) g[q] += __shfl_xor(g[q], m, 64);

    // Hand off to LDS (one writer per group; static q indices only).
    if (s == 0) {
        const int slot = wave * 8 + grp;
#pragma unroll
        for (int q = 0; q < 15; ++q) lds_g[slot][q] = g[q];
    }
    __syncthreads();

    // ---- Phase 2: one wave, one item per lane ----
    if (tid < 32) {
        const long item2 = (long)blockIdx.x * 32 + tid;

        double h[15];
#pragma unroll
        for (int q = 0; q < 15; ++q) h[q] = lds_g[tid][q];

        // Edge statistics over the 10 pairwise distances (ddof=1).
        double e[10];
        double se = 0.0;
        {
            int q = 0;
#pragma unroll
            for (int i = 0; i < 5; ++i)
#pragma unroll
                for (int j = i + 1; j < 5; ++j) {
                    double d2 = fma(-2.0, h[gidx(i, j)],
                                    h[gidx(i, i)] + h[gidx(j, j)]);
                    e[q] = sqrt(d2);
                    se += e[q];
                    ++q;
                }
        }
        double meanE = se * 0.1;
        double ve = 0.0;
#pragma unroll
        for (int q = 0; q < 10; ++q) {
            double d = e[q] - meanE;
            ve = fma(d, d, ve);
        }
        double stdE = sqrt(ve / 9.0);

        // Row sums S[i] = sum_j G[i][j], total T.
        double S[5], T = 0.0;
#pragma unroll
        for (int i = 0; i < 5; ++i) {
            double si = 0.0;
#pragma unroll
            for (int j = 0; j < 5; ++j) {
                int a = i < j ? i : j;
                int b = i < j ? j : i;
                si += h[gidx(a, b)];
            }
            S[i] = si;
            T += si;
        }

        // Vertex spread (ddof=1 over 5 centroid distances).
        double scd = 0.0, cd[5];
#pragma unroll
        for (int v = 0; v < 5; ++v) {
            double c2 = fma(-0.4, S[v], h[gidx(v, v)]) + 0.04 * T;
            cd[v] = (c2 > 0.0) ? sqrt(c2) : 0.0;
            scd += cd[v];
        }
        double meanC = scd * 0.2;
        double vc = 0.0;
#pragma unroll
        for (int v = 0; v < 5; ++v) {
            double d = cd[v] - meanC;
            vc = fma(d, d, vc);
        }
        double spread = sqrt(vc * 0.25);

        // W[pq] = (x_p - x_0)·(x_q - x_0), p,q in 1..4 (PSD) ->
        // det M6 = -16 det W; volume^2 = det W / 576.
        double W[4][4];
#pragma unroll
        for (int pi = 0; pi < 4; ++pi)
#pragma unroll
            for (int qi = 0; qi < 4; ++qi) {
                int a0 = 0, b0 = qi + 1;
                int a1 = 0, b1 = pi + 1;
                int lo = (pi < qi ? pi : qi) + 1;
                int hi = (pi < qi ? qi : pi) + 1;
                W[pi][qi] = h[gidx(lo, hi)] - h[gidx(a0, b0)]
                          - h[gidx(a1, b1)] + h[gidx(0, 0)];
            }

        double det = 1.0;
#pragma unroll
        for (int k = 0; k < 4; ++k) {
            double pv = W[k][k];
            det *= pv;
            double inv = (pv != 0.0) ? 1.0 / pv : 0.0;
#pragma unroll
            for (int r = k + 1; r < 4; ++r) {
                double fac = W[r][k] * inv;
#pragma unroll
                for (int c = k + 1; c < 4; ++c)
                    W[r][c] = fma(-fac, W[k][c], W[r][c]);
            }
        }

        double v2 = det / 576.0;
        double volume = (v2 > 0.0) ? sqrt(v2) : 0.0;

        double vn = 1.0 / (1.0 + exp(-10.0 * volume));
        double er = 1.0 / (1.0 + exp(-(stdE / (meanE + 1e-6))));
        double sn = 1.0 / (1.0 + exp(-spread));

        double seed = 0.4 * vn + 0.3 * er + 0.3 * sn;
        seed = fmin(fmax(seed, 1e-6), 1.0 - 1e-6);
        double drift = (vn + er + sn) * 0.01;

        double x = seed, cv = 0.0, factor = 0.5;
#pragma unroll
        for (int k = 0; k < 8; ++k) {
            double xs = x * 3.0;
            double dg = floor(xs);
            double fr = xs - dg;
            cv += (dg == 2.0) ? factor : 0.0;
            factor *= 0.5;
            x = fmin(fmax(fr + drift, 1e-6), 1.0 - 1e-6);
        }
        cv = fmin(fmax(cv, 0.0), 1.0);

        if (item2 < nItems)
            out[item2] = (float)cv;
    }
}

extern "C" void kernel_launch(void* const* d_in, const int* in_sizes, int n_in,
                              void* d_out, int out_size, void* d_ws, size_t ws_size,
                              hipStream_t stream) {
    const float* pent = (const float*)d_in[0];
    float* out = (float*)d_out;
    int nItems = in_sizes[0] / 640;            // 5*128 floats per item
    int blocks = (nItems + 31) / 32;           // 32 items per 256-thread block
    hipLaunchKernelGGL(fingerprint_kernel, dim3(blocks), dim3(256), 0, stream,
                       pent, out, nItems);
}